// Round 5
// baseline (41.630 us; speedup 1.0000x reference)
//
#include <hip/hip_runtime.h>

// 3D median filter 3x3x3, stride 1, reflect padding.
// x: (2, 1, 160, 160, 160) fp32 -> same shape. Median = rank 13 (0-based) of 27.
// Packed-f16: each lane computes 2 x-adjacent outputs via v_pk_min/max_f16.
// merge99 of the shared plane pair serves 2 z-outputs.
// Round 4: latency-bound fix = TLP. CH 10 -> 4 (2.5x waves, 15.6/SIMD),
// __launch_bounds__(256,8) pins VGPR<=64 so 8 waves/SIMD stay resident.

typedef __fp16 hf2 __attribute__((ext_vector_type(2)));

#define DEV __device__ __forceinline__

DEV hf2 hmin2(hf2 a, hf2 b) { return __builtin_elementwise_min(a, b); }
DEV hf2 hmax2(hf2 a, hf2 b) { return __builtin_elementwise_max(a, b); }
DEV void ce(hf2& a, hf2& b) { hf2 lo = hmin2(a, b); hf2 hi = hmax2(a, b); a = lo; b = hi; }
DEV hf2 pk2(float a, float b) { return __builtin_amdgcn_cvt_pkrtz(a, b); }

DEV void sort3(hf2& a, hf2& b, hf2& c) { ce(a, b); ce(a, c); ce(b, c); }

// Batcher odd-even merges of small sorted sequences (verified exact in round 1).
DEV void merge21(hf2 a0, hf2 a1, hf2 b0, hf2 z[3]) {
    hf2 e0 = a0, e1 = b0; ce(e0, e1);
    z[0] = e0; z[1] = a1; z[2] = e1; ce(z[1], z[2]);
}
DEV void merge22(hf2 a0, hf2 a1, hf2 b0, hf2 b1, hf2 z[4]) {
    hf2 p0 = a0, p1 = b0; ce(p0, p1);
    hf2 q0 = a1, q1 = b1; ce(q0, q1);
    z[0] = p0; z[1] = q0; z[2] = p1; ce(z[1], z[2]); z[3] = q1;
}
DEV void merge31(hf2 a0, hf2 a1, hf2 a2, hf2 b0, hf2 z[4]) {
    hf2 e[3]; merge21(a0, a2, b0, e);
    z[0] = e[0]; z[1] = a1; z[2] = e[1]; ce(z[1], z[2]); z[3] = e[2];
}
DEV void merge32(hf2 a0, hf2 a1, hf2 a2, hf2 b0, hf2 b1, hf2 z[5]) {
    hf2 e[3]; merge21(a0, a2, b0, e);
    hf2 o0 = a1, o1 = b1; ce(o0, o1);
    z[0] = e[0];
    z[1] = o0; z[2] = e[1]; ce(z[1], z[2]);
    z[3] = o1; z[4] = e[2]; ce(z[3], z[4]);
}
DEV void merge33(const hf2 a[3], const hf2 b[3], hf2 z[6]) {
    hf2 e[4]; merge22(a[0], a[2], b[0], b[2], e);
    hf2 o0 = a[1], o1 = b[1]; ce(o0, o1);
    z[0] = e[0];
    z[1] = o0; z[2] = e[1]; ce(z[1], z[2]);
    z[3] = o1; z[4] = e[2]; ce(z[3], z[4]);
    z[5] = e[3];
}
DEV void merge63(const hf2 a[6], const hf2 b[3], hf2 z[9]) {
    hf2 e[5]; merge32(a[0], a[2], a[4], b[0], b[2], e);
    hf2 o[4]; merge31(a[1], a[3], a[5], b[1], o);
    z[0] = e[0];
    z[1] = o[0]; z[2] = e[1]; ce(z[1], z[2]);
    z[3] = o[1]; z[4] = e[2]; ce(z[3], z[4]);
    z[5] = o[2]; z[6] = e[3]; ce(z[5], z[6]);
    z[7] = o[3]; z[8] = e[4]; ce(z[7], z[8]);
}
DEV void merge44(const hf2 a[4], const hf2 b[4], hf2 z[8]) {
    hf2 e[4]; merge22(a[0], a[2], b[0], b[2], e);
    hf2 o[4]; merge22(a[1], a[3], b[1], b[3], o);
    z[0] = e[0];
    z[1] = o[0]; z[2] = e[1]; ce(z[1], z[2]);
    z[3] = o[1]; z[4] = e[2]; ce(z[3], z[4]);
    z[5] = o[2]; z[6] = e[3]; ce(z[5], z[6]);
    z[7] = o[3];
}
DEV void merge55(const hf2 a[5], const hf2 b[5], hf2 z[10]) {
    hf2 ae[3] = {a[0], a[2], a[4]}, be[3] = {b[0], b[2], b[4]};
    hf2 e[6]; merge33(ae, be, e);
    hf2 o[4]; merge22(a[1], a[3], b[1], b[3], o);
    z[0] = e[0];
    z[1] = o[0]; z[2] = e[1]; ce(z[1], z[2]);
    z[3] = o[1]; z[4] = e[2]; ce(z[3], z[4]);
    z[5] = o[2]; z[6] = e[3]; ce(z[5], z[6]);
    z[7] = o[3]; z[8] = e[4]; ce(z[7], z[8]);
    z[9] = e[5];
}
DEV void merge99(const hf2 a[9], const hf2 b[9], hf2 z[18]) {
    hf2 ae[5] = {a[0], a[2], a[4], a[6], a[8]};
    hf2 be[5] = {b[0], b[2], b[4], b[6], b[8]};
    hf2 e[10]; merge55(ae, be, e);
    hf2 ao[4] = {a[1], a[3], a[5], a[7]};
    hf2 bo[4] = {b[1], b[3], b[5], b[7]};
    hf2 o[8]; merge44(ao, bo, o);
    z[0] = e[0];
#pragma unroll
    for (int i = 0; i < 8; i++) {
        z[2 * i + 1] = o[i];
        z[2 * i + 2] = e[i + 1];
        ce(z[2 * i + 1], z[2 * i + 2]);
    }
    z[17] = e[9];
}

// Raw taps of the 3x3 (y,x) window of plane `pb` -> 12 floats (no compute).
DEV void load_plane(const float* __restrict__ pb, const int ro[3], int c0, int x0, int c3,
                    float R[12]) {
#pragma unroll
    for (int i = 0; i < 3; i++) {
        const float* p = pb + ro[i];
        R[i * 4 + 0] = p[c0];
        float2 bc = *reinterpret_cast<const float2*>(p + x0);  // 8B-aligned (x0 even)
        R[i * 4 + 1] = bc.x;
        R[i * 4 + 2] = bc.y;
        R[i * 4 + 3] = p[c3];
    }
}

// 12 raw floats -> packed rows -> sorted-9 (packed x2).
DEV void sort_plane(const float R[12], hf2 M[9]) {
    hf2 r[3][3];
#pragma unroll
    for (int i = 0; i < 3; i++) {
        r[i][0] = pk2(R[i * 4 + 0], R[i * 4 + 1]);  // left taps of (x0, x0+1)
        r[i][1] = pk2(R[i * 4 + 1], R[i * 4 + 2]);  // center taps
        r[i][2] = pk2(R[i * 4 + 2], R[i * 4 + 3]);  // right taps
        sort3(r[i][0], r[i][1], r[i][2]);
    }
    hf2 s6[6]; merge33(r[0], r[1], s6);
    merge63(s6, r[2], M);
}

// rank-13-of-27 from merged-18 E and sorted-9 R:
//   med = min(E[13], min_i max(R[i], E[12-i]))   (verified exact in round 1)
DEV hf2 sel13(const hf2 E[18], const hf2 R[9]) {
    hf2 m = E[13];
#pragma unroll
    for (int i = 0; i < 9; i++) m = hmin2(m, hmax2(R[i], E[12 - i]));
    return m;
}

constexpr int Bb = 2, Dd = 160, Hh = 160, Ww = 160;
constexpr int HW = Hh * Ww;           // 25600
constexpr int WP = Ww / 2;            // 80 packed-x pairs
constexpr int TP = Hh * WP;           // 12800 threads per (b, chunk)
constexpr int CH = 4;                 // z-chunk per thread (even)
constexpr int NCH = Dd / CH;          // 40
constexpr int TOTAL = Bb * NCH * TP;  // 1,024,000 threads = 16,000 waves

__global__ __launch_bounds__(256, 8) void MedianPool3d_68994354642979_kernel(
    const float* __restrict__ in, float* __restrict__ out) {
    int tid = blockIdx.x * 256 + threadIdx.x;
    int t = tid % TP;
    int co = tid / TP;
    int b = co / NCH;
    int chunk = co - b * NCH;
    int y = t / WP;
    int px = t - y * WP;
    int x0 = px * 2;

    // reflect padding (jnp.pad mode="reflect", pad=1)
    int ym = (y == 0) ? 1 : y - 1;
    int yp = (y == Hh - 1) ? Hh - 2 : y + 1;
    int ro[3] = {ym * Ww, y * Ww, yp * Ww};
    int c0 = (x0 == 0) ? 1 : x0 - 1;               // left tap of x0
    int c3 = (x0 == Ww - 2) ? (Ww - 2) : x0 + 2;   // right tap of x0+1

    const float* base = in + (size_t)b * Dd * HW;
    float* ob = out + (size_t)b * Dd * HW;
    int z0 = chunk * CH;

    auto planeptr = [&](int p) {
        if (p < 0) p = -p;                 // reflect(-1) = 1
        if (p >= Dd) p = 2 * Dd - 2 - p;   // reflect(160) = 158
        return base + (size_t)p * HW;
    };

    // Sorted ring: plane rel r (= plane - z0, r in [-1, CH]) lives in slot (r+1)%5.
    hf2 SS[5][9];
    // Raw double-buffer: RT[j&1] = the (up to) two planes consumed at iteration j.
    float RT[2][2][12];

    {   // prologue: planes rel -1, 0, 1
        float P0[12], P1[12], P2[12];
        load_plane(planeptr(z0 - 1), ro, c0, x0, c3, P0);
        load_plane(planeptr(z0),     ro, c0, x0, c3, P1);
        load_plane(planeptr(z0 + 1), ro, c0, x0, c3, P2);
        sort_plane(P0, SS[0]);
        sort_plane(P1, SS[1]);
        sort_plane(P2, SS[2]);
    }
    // raw planes rel 2, 3 for iteration 0
    load_plane(planeptr(z0 + 2), ro, c0, x0, c3, RT[0][0]);
    load_plane(planeptr(z0 + 3), ro, c0, x0, c3, RT[0][1]);

#pragma unroll
    for (int j = 0; j < CH / 2; j++) {
        const int z = z0 + 2 * j;
        // ring slots (compile-time under full unroll)
        const int sA = (2 * j) % 5;      // S[z-1]
        const int sB = (2 * j + 1) % 5;  // S[z]
        const int sC = (2 * j + 2) % 5;  // S[z+1]
        const int sD = (2 * j + 3) % 5;  // S[z+2]
        const int sE = (2 * j + 4) % 5;  // S[z+3]
        const int cb = j & 1, nb = cb ^ 1;

        // next iteration's raw loads (issued early; consumed next iteration)
        if (j + 1 < CH / 2) {
            load_plane(planeptr(z + 4), ro, c0, x0, c3, RT[nb][0]);
            if (2 * (j + 1) + 3 <= CH)
                load_plane(planeptr(z + 5), ro, c0, x0, c3, RT[nb][1]);
        }

        // sort the planes loaded last iteration
        sort_plane(RT[cb][0], SS[sD]);                       // plane rel 2j+2
        if (2 * j + 3 <= CH) sort_plane(RT[cb][1], SS[sE]);  // plane rel 2j+3

        hf2 E[18];
        merge99(SS[sB], SS[sC], E);       // shared pair (z, z+1) -> used twice
        hf2 med0 = sel13(E, SS[sA]);      // output z   : third plane z-1
        hf2 med1 = sel13(E, SS[sD]);      // output z+1 : third plane z+2

        float* o0 = ob + (size_t)z * HW + ro[1] + x0;
        float* o1 = o0 + HW;
        *reinterpret_cast<float2*>(o0) = make_float2((float)med0[0], (float)med0[1]);
        *reinterpret_cast<float2*>(o1) = make_float2((float)med1[0], (float)med1[1]);
    }
}

extern "C" void kernel_launch(void* const* d_in, const int* in_sizes, int n_in,
                              void* d_out, int out_size, void* d_ws, size_t ws_size,
                              hipStream_t stream) {
    const float* x = (const float*)d_in[0];
    float* out = (float*)d_out;
    constexpr int threads = 256;
    constexpr int blocks = TOTAL / threads;  // 4000 exactly
    MedianPool3d_68994354642979_kernel<<<blocks, threads, 0, stream>>>(x, out);
}

// Round 6
// 28.351 us; speedup vs baseline: 1.4684x; 1.4684x over previous
//
#include <hip/hip_runtime.h>

// 3D median filter 3x3x3, stride 1, reflect padding.
// x: (2, 1, 160, 160, 160) fp32 -> same shape. Median = rank 13 (0-based) of 27.
// Round 5: 4 outputs per thread in x, packed as one hf4 (two independent
// packed-f16 pairs) -> v_pk_min/max_f16 at 4 elems per 2 ops, 2x ILP,
// 2.25 vmem/output (dword + dwordx4 + dword per row). 4-slot sorted ring.

typedef __fp16 hf2 __attribute__((ext_vector_type(2)));
typedef __fp16 hf4 __attribute__((ext_vector_type(4)));

#define DEV __device__ __forceinline__

DEV hf4 hmin4(hf4 a, hf4 b) { return __builtin_elementwise_min(a, b); }
DEV hf4 hmax4(hf4 a, hf4 b) { return __builtin_elementwise_max(a, b); }
DEV void ce(hf4& a, hf4& b) { hf4 lo = hmin4(a, b); hf4 hi = hmax4(a, b); a = lo; b = hi; }
DEV hf2 pk2(float a, float b) { return __builtin_amdgcn_cvt_pkrtz(a, b); }
DEV hf4 cat(hf2 a, hf2 b) { return __builtin_shufflevector(a, b, 0, 1, 2, 3); }

DEV void sort3(hf4& a, hf4& b, hf4& c) { ce(a, b); ce(a, c); ce(b, c); }

// Batcher odd-even merges of small sorted sequences (verified exact in round 1).
DEV void merge21(hf4 a0, hf4 a1, hf4 b0, hf4 z[3]) {
    hf4 e0 = a0, e1 = b0; ce(e0, e1);
    z[0] = e0; z[1] = a1; z[2] = e1; ce(z[1], z[2]);
}
DEV void merge22(hf4 a0, hf4 a1, hf4 b0, hf4 b1, hf4 z[4]) {
    hf4 p0 = a0, p1 = b0; ce(p0, p1);
    hf4 q0 = a1, q1 = b1; ce(q0, q1);
    z[0] = p0; z[1] = q0; z[2] = p1; ce(z[1], z[2]); z[3] = q1;
}
DEV void merge31(hf4 a0, hf4 a1, hf4 a2, hf4 b0, hf4 z[4]) {
    hf4 e[3]; merge21(a0, a2, b0, e);
    z[0] = e[0]; z[1] = a1; z[2] = e[1]; ce(z[1], z[2]); z[3] = e[2];
}
DEV void merge32(hf4 a0, hf4 a1, hf4 a2, hf4 b0, hf4 b1, hf4 z[5]) {
    hf4 e[3]; merge21(a0, a2, b0, e);
    hf4 o0 = a1, o1 = b1; ce(o0, o1);
    z[0] = e[0];
    z[1] = o0; z[2] = e[1]; ce(z[1], z[2]);
    z[3] = o1; z[4] = e[2]; ce(z[3], z[4]);
}
DEV void merge33(const hf4 a[3], const hf4 b[3], hf4 z[6]) {
    hf4 e[4]; merge22(a[0], a[2], b[0], b[2], e);
    hf4 o0 = a[1], o1 = b[1]; ce(o0, o1);
    z[0] = e[0];
    z[1] = o0; z[2] = e[1]; ce(z[1], z[2]);
    z[3] = o1; z[4] = e[2]; ce(z[3], z[4]);
    z[5] = e[3];
}
DEV void merge63(const hf4 a[6], const hf4 b[3], hf4 z[9]) {
    hf4 e[5]; merge32(a[0], a[2], a[4], b[0], b[2], e);
    hf4 o[4]; merge31(a[1], a[3], a[5], b[1], o);
    z[0] = e[0];
    z[1] = o[0]; z[2] = e[1]; ce(z[1], z[2]);
    z[3] = o[1]; z[4] = e[2]; ce(z[3], z[4]);
    z[5] = o[2]; z[6] = e[3]; ce(z[5], z[6]);
    z[7] = o[3]; z[8] = e[4]; ce(z[7], z[8]);
}
DEV void merge44(const hf4 a[4], const hf4 b[4], hf4 z[8]) {
    hf4 e[4]; merge22(a[0], a[2], b[0], b[2], e);
    hf4 o[4]; merge22(a[1], a[3], b[1], b[3], o);
    z[0] = e[0];
    z[1] = o[0]; z[2] = e[1]; ce(z[1], z[2]);
    z[3] = o[1]; z[4] = e[2]; ce(z[3], z[4]);
    z[5] = o[2]; z[6] = e[3]; ce(z[5], z[6]);
    z[7] = o[3];
}
DEV void merge55(const hf4 a[5], const hf4 b[5], hf4 z[10]) {
    hf4 ae[3] = {a[0], a[2], a[4]}, be[3] = {b[0], b[2], b[4]};
    hf4 e[6]; merge33(ae, be, e);
    hf4 o[4]; merge22(a[1], a[3], b[1], b[3], o);
    z[0] = e[0];
    z[1] = o[0]; z[2] = e[1]; ce(z[1], z[2]);
    z[3] = o[1]; z[4] = e[2]; ce(z[3], z[4]);
    z[5] = o[2]; z[6] = e[3]; ce(z[5], z[6]);
    z[7] = o[3]; z[8] = e[4]; ce(z[7], z[8]);
    z[9] = e[5];
}
DEV void merge99(const hf4 a[9], const hf4 b[9], hf4 z[18]) {
    hf4 ae[5] = {a[0], a[2], a[4], a[6], a[8]};
    hf4 be[5] = {b[0], b[2], b[4], b[6], b[8]};
    hf4 e[10]; merge55(ae, be, e);
    hf4 ao[4] = {a[1], a[3], a[5], a[7]};
    hf4 bo[4] = {b[1], b[3], b[5], b[7]};
    hf4 o[8]; merge44(ao, bo, o);
    z[0] = e[0];
#pragma unroll
    for (int i = 0; i < 8; i++) {
        z[2 * i + 1] = o[i];
        z[2 * i + 2] = e[i + 1];
        ce(z[2 * i + 1], z[2 * i + 2]);
    }
    z[17] = e[9];
}

// Sorted-9 (4-wide packed) of the 3x3 (y,x) windows for columns x0..x0+3.
// cL/cR are the reflected outer columns (x0-1, x0+4).
DEV void sort_plane(const float* __restrict__ pb, const int ro[3], int cL, int x0, int cR,
                    hf4 M[9]) {
    hf4 r[3][3];
#pragma unroll
    for (int i = 0; i < 3; i++) {
        const float* p = pb + ro[i];
        float a = p[cL];
        float4 v = *reinterpret_cast<const float4*>(p + x0);  // 16B-aligned (x0 % 4 == 0)
        float d = p[cR];
        hf2 pAL = pk2(a, v.x);
        hf2 pAC = pk2(v.x, v.y);
        hf2 pSH = pk2(v.y, v.z);   // right-taps of pair A == left-taps of pair B
        hf2 pBC = pk2(v.z, v.w);
        hf2 pBR = pk2(v.w, d);
        r[i][0] = cat(pAL, pSH);   // left taps  {A, B}
        r[i][1] = cat(pAC, pBC);   // center taps
        r[i][2] = cat(pSH, pBR);   // right taps
        sort3(r[i][0], r[i][1], r[i][2]);
    }
    hf4 s6[6]; merge33(r[0], r[1], s6);
    merge63(s6, r[2], M);
}

// rank-13-of-27 from merged-18 E and sorted-9 R:
//   med = min(E[13], min_i max(R[i], E[12-i]))   (verified exact in round 1)
DEV hf4 sel13(const hf4 E[18], const hf4 R[9]) {
    hf4 m = E[13];
#pragma unroll
    for (int i = 0; i < 9; i++) m = hmin4(m, hmax4(R[i], E[12 - i]));
    return m;
}

constexpr int Bb = 2, Dd = 160, Hh = 160, Ww = 160;
constexpr int HW = Hh * Ww;            // 25600
constexpr int WQ = Ww / 4;             // 40 x-quads per row
constexpr int TPC = Hh * WQ;           // 6400 threads per (b, chunk)
constexpr int CH = 8;                  // z-chunk per thread (even)
constexpr int NCH = Dd / CH;           // 20
constexpr int TOTAL = Bb * NCH * TPC;  // 256,000 threads = 4000 waves

__global__ __launch_bounds__(256, 4) void MedianPool3d_68994354642979_kernel(
    const float* __restrict__ in, float* __restrict__ out) {
    int tid = blockIdx.x * 256 + threadIdx.x;
    int q = tid % WQ;
    int rest = tid / WQ;
    int y = rest % Hh;
    rest /= Hh;
    int chunk = rest % NCH;
    int b = rest / NCH;
    int x0 = q * 4;

    // reflect padding (jnp.pad mode="reflect", pad=1)
    int ym = (y == 0) ? 1 : y - 1;
    int yp = (y == Hh - 1) ? Hh - 2 : y + 1;
    int ro[3] = {ym * Ww, y * Ww, yp * Ww};
    int cL = (x0 == 0) ? 1 : x0 - 1;                 // left tap of col x0
    int cR = (x0 + 4 == Ww) ? (Ww - 2) : x0 + 4;     // right tap of col x0+3

    const float* base = in + (size_t)b * Dd * HW;
    float* ob = out + (size_t)b * Dd * HW;
    int z0 = chunk * CH;

    auto planeptr = [&](int p) {
        if (p < 0) p = -p;                 // reflect(-1) = 1
        if (p >= Dd) p = 2 * Dd - 2 - p;   // reflect(160) = 158
        return base + (size_t)p * HW;
    };

    // 4-slot ring of sorted planes: plane rel r (r in [-1, CH]) -> slot (r+1)&3.
    // S[z+3] overwrites S[z-1]'s slot after S[z-1]'s last use (sel13 of output z).
    hf4 SS[4][9];
    sort_plane(planeptr(z0 - 1), ro, cL, x0, cR, SS[0]);
    sort_plane(planeptr(z0),     ro, cL, x0, cR, SS[1]);
    sort_plane(planeptr(z0 + 1), ro, cL, x0, cR, SS[2]);

#pragma unroll
    for (int j = 0; j < CH / 2; j++) {
        const int z = z0 + 2 * j;
        const int sA = (2 * j) & 3;      // S[z-1]
        const int sB = (2 * j + 1) & 3;  // S[z]
        const int sC = (2 * j + 2) & 3;  // S[z+1]
        const int sD = (2 * j + 3) & 3;  // S[z+2]

        sort_plane(planeptr(z + 2), ro, cL, x0, cR, SS[sD]);

        hf4 E[18];
        merge99(SS[sB], SS[sC], E);       // shared pair (z, z+1) -> used twice
        hf4 m0 = sel13(E, SS[sA]);        // output z   : third plane z-1
        hf4 m1 = sel13(E, SS[sD]);        // output z+1 : third plane z+2

        float* o0 = ob + (size_t)z * HW + ro[1] + x0;   // 16B-aligned
        float* o1 = o0 + HW;
        *reinterpret_cast<float4*>(o0) =
            make_float4((float)m0.x, (float)m0.y, (float)m0.z, (float)m0.w);
        *reinterpret_cast<float4*>(o1) =
            make_float4((float)m1.x, (float)m1.y, (float)m1.z, (float)m1.w);

        if (j < CH / 2 - 1)  // sort S[z+3] into the retired slot (skip on last iter)
            sort_plane(planeptr(z + 3), ro, cL, x0, cR, SS[sA]);
    }
}

extern "C" void kernel_launch(void* const* d_in, const int* in_sizes, int n_in,
                              void* d_out, int out_size, void* d_ws, size_t ws_size,
                              hipStream_t stream) {
    const float* x = (const float*)d_in[0];
    float* out = (float*)d_out;
    constexpr int threads = 256;
    constexpr int blocks = TOTAL / threads;  // 1000 exactly
    MedianPool3d_68994354642979_kernel<<<blocks, threads, 0, stream>>>(x, out);
}